// Round 10
// baseline (109.491 us; speedup 1.0000x reference)
//
#include <hip/hip_runtime.h>

// TT-linear fp32, fully fused, zero workspace. Phase C (57% of FLOPs) on
// matrix cores via bf16x3 split (hi+lo bf16, 3 MFMAs ~ fp32 accuracy).
//
// x:     [128][8192], i = i0*256 + i1*16 + i2   (i0:32, i1:16, i2:16)
// core0: c0[o0*128 + k], k = i0*4 + r1          (o0:32, r1:4)
// core1: c1[(r1*16+o1)*64 + j], j = i1*4 + r2   (o1:16, r2:4)
// core2: c2[r2*256 + o2*16 + i2]                (o2:16)
// out:   [128][8192], o = o0*256 + o1*16 + o2
//
// Block (t, o2-quarter q), 512 thr (8 waves):
//   B: y1[j(64)][col(128)] computed scalar, written as bf16 hi/lo planes in
//      MFMA B-fragment order: y1f[cg=(s,tile_n)][plane][lane] 16B chunks
//      (lane: n=lane&15 -> col, g=lane>>4 -> k-subblock; stride-16B = conflict-free).
//   C: y2[m=(o1,r1)][col] = c1 . y1 via mfma_f32_16x16x32_bf16, wave ->
//      (tile_m = w>>1, 4 n-tiles); A-frags (c1 hi/lo) in VGPRs from global.
//      C/D layout (col=lane&15, row=(lane>>4)*4+reg) + m-order o1*4+r1 makes
//      reg 0..3 = k-quad contiguous -> one float4 store per tile into y2t.
//   D: out = c0 . y2 + bias, scalar FMA; y2t[dcol][k pad 140] b128 reads.

typedef float  f32x4 __attribute__((ext_vector_type(4)));
typedef __bf16 bf16x8 __attribute__((ext_vector_type(8)));

__device__ __forceinline__ float dot4(float4 a, float4 b) {
    return a.x*b.x + a.y*b.y + a.z*b.z + a.w*b.w;
}

__global__ __launch_bounds__(512, 4) void tt_fused(
    const float* __restrict__ x, const float* __restrict__ c0,
    const float* __restrict__ c1, const float* __restrict__ c2,
    const float* __restrict__ bias, float* __restrict__ out)
{
    __shared__ bf16x8 y1f[2048];                 // [cg(16)][plane(2)][lane(64)], 32 KB
    __shared__ __align__(16) float y2t[8960];    // [dcol(64)][k(128) pad->140], 35 KB

    const int tid = threadIdx.x;
    const int w = tid >> 6, lane = tid & 63;
    const int g = lane >> 4, n = lane & 15;
    const int b = blockIdx.x;
    const int t = b >> 2, q = b & 3;

    // ---- A-fragments (c1, hi/lo) for phase C — early, VMEM overlaps B ------
    const int tile_m = w >> 1;
    bf16x8 Ah[2], Al[2];
    {
        const int m = tile_m*16 + n;             // m-order: m = o1*4 + r1
        const int r1 = m & 3, o1 = m >> 2;
        const float* cp = c1 + (r1*16 + o1)*64 + 8*g;
#pragma unroll
        for (int s = 0; s < 2; ++s) {
            float4 a0 = *reinterpret_cast<const float4*>(cp + 32*s);
            float4 a1 = *reinterpret_cast<const float4*>(cp + 32*s + 4);
            const float av[8] = {a0.x,a0.y,a0.z,a0.w, a1.x,a1.y,a1.z,a1.w};
#pragma unroll
            for (int d = 0; d < 8; ++d) {
                __bf16 h = (__bf16)av[d];
                Ah[s][d] = h;
                Al[s][d] = (__bf16)(av[d] - (float)h);
            }
        }
    }

    // ---- Phase B: y1 fragments, 2 chunks per thread ------------------------
    {
        const int o2 = q*4 + (n & 3);
#pragma unroll
        for (int c = 0; c < 2; ++c) {
            const int cg = 2*w + c;
            const int s = cg >> 3, tn = cg & 7;
            const int i0 = tn*4 + (n >> 2);
            const int i1b = 8*s + 2*g;           // even: 2 slices contiguous
            const float4* xq = reinterpret_cast<const float4*>(
                x + t*8192 + i0*256 + i1b*16);
            const float4 xa0 = xq[0], xa1 = xq[1], xa2 = xq[2], xa3 = xq[3];
            const float4 xb0 = xq[4], xb1 = xq[5], xb2 = xq[6], xb3 = xq[7];
            float sv[8];
#pragma unroll
            for (int r2 = 0; r2 < 4; ++r2) {     // c2: 4-addr broadcast, L1/L2
                const float4* cb = reinterpret_cast<const float4*>(c2 + r2*256 + o2*16);
                const float4 c20 = cb[0], c21 = cb[1], c22 = cb[2], c23 = cb[3];
                sv[r2]   = dot4(xa0,c20)+dot4(xa1,c21)+dot4(xa2,c22)+dot4(xa3,c23);
                sv[4+r2] = dot4(xb0,c20)+dot4(xb1,c21)+dot4(xb2,c22)+dot4(xb3,c23);
            }
            bf16x8 hi, lo;
#pragma unroll
            for (int d = 0; d < 8; ++d) {
                __bf16 h = (__bf16)sv[d];
                hi[d] = h;
                lo[d] = (__bf16)(sv[d] - (float)h);
            }
            y1f[(cg*2 + 0)*64 + lane] = hi;      // stride-16B: conflict-free
            y1f[(cg*2 + 1)*64 + lane] = lo;
        }
    }
    __syncthreads();

    // ---- Phase C: MFMA, 24 per wave (4 n-tiles x 2 K-steps x 3 split) ------
    {
        const int tnb = (w & 1)*4;
        f32x4 acc[4] = {{0,0,0,0},{0,0,0,0},{0,0,0,0},{0,0,0,0}};
#pragma unroll
        for (int tt = 0; tt < 4; ++tt) {
#pragma unroll
            for (int s = 0; s < 2; ++s) {
                const int cg = s*8 + tnb + tt;
                const bf16x8 Bh = y1f[(cg*2 + 0)*64 + lane];
                const bf16x8 Bl = y1f[(cg*2 + 1)*64 + lane];
                acc[tt] = __builtin_amdgcn_mfma_f32_16x16x32_bf16(Ah[s], Bh, acc[tt], 0, 0, 0);
                acc[tt] = __builtin_amdgcn_mfma_f32_16x16x32_bf16(Ah[s], Bl, acc[tt], 0, 0, 0);
                acc[tt] = __builtin_amdgcn_mfma_f32_16x16x32_bf16(Al[s], Bh, acc[tt], 0, 0, 0);
            }
        }
        // reg r <-> row m = tile_m*16 + g*4 + r -> r1 = r, o1 = tile_m*4 + g:
        // the 4 regs are k = 4*i0..4*i0+3 contiguous -> one float4 per tile.
        const int dcol = (tile_m*4 + g)*4 + (n & 3);
#pragma unroll
        for (int tt = 0; tt < 4; ++tt) {
            const int i0 = (tnb + tt)*4 + (n >> 2);
            *reinterpret_cast<float4*>(y2t + dcol*140 + i0*4) =
                make_float4(acc[tt][0], acc[tt][1], acc[tt][2], acc[tt][3]);
        }
    }
    __syncthreads();

    // ---- Phase D: out = c0 . y2 + bias (scalar FMA) ------------------------
    {
        const int o0q = w;                        // wave-grouped rows
        const int dcol = lane;
        const float* yrow = y2t + dcol*140;
        const float* c0p = c0 + o0q*4*128;
        float a0 = 0.f, a1 = 0.f, a2 = 0.f, a3 = 0.f;
#pragma unroll 4
        for (int kq = 0; kq < 32; ++kq) {
            const float4 yv = *reinterpret_cast<const float4*>(yrow + kq*4);
            const float4 q0 = *reinterpret_cast<const float4*>(c0p + 0*128 + kq*4);
            const float4 q1 = *reinterpret_cast<const float4*>(c0p + 1*128 + kq*4);
            const float4 q2 = *reinterpret_cast<const float4*>(c0p + 2*128 + kq*4);
            const float4 q3 = *reinterpret_cast<const float4*>(c0p + 3*128 + kq*4);
            a0 += dot4(q0, yv); a1 += dot4(q1, yv);
            a2 += dot4(q2, yv); a3 += dot4(q3, yv);
        }
        const int ob = o0q*1024 + (dcol >> 2)*16 + q*4 + (dcol & 3);
        float* op = out + t*8192 + ob;
        op[0]   = a0 + bias[ob];
        op[256] = a1 + bias[ob + 256];
        op[512] = a2 + bias[ob + 512];
        op[768] = a3 + bias[ob + 768];
    }
}

extern "C" void kernel_launch(void* const* d_in, const int* in_sizes, int n_in,
                              void* d_out, int out_size, void* d_ws, size_t ws_size,
                              hipStream_t stream) {
    const float* x    = (const float*)d_in[0];
    const float* c0   = (const float*)d_in[1];
    const float* c1   = (const float*)d_in[2];
    const float* c2   = (const float*)d_in[3];
    const float* bias = (const float*)d_in[4];
    float* out = (float*)d_out;
    (void)d_ws; (void)ws_size;    // no workspace — intermediates live in LDS

    tt_fused<<<512, 512, 0, stream>>>(x, c0, c1, c2, bias, out);
}

// Round 11
// 95.104 us; speedup vs baseline: 1.1513x; 1.1513x over previous
//
#include <hip/hip_runtime.h>

// TT-linear fp32, fully fused, zero workspace. Phase C (57% of FLOPs) on
// matrix cores via bf16x3 split (hi+lo bf16, 3 MFMAs ~ fp32 accuracy).
// R11: spill fix — launch_bounds(512,2) (VGPR cap 128, occupancy still
// LDS-capped at 2 blocks/CU) + phase B processes x slices sequentially
// (peak live regs ~60, was ~90 under a 64-reg budget -> 49 MB scratch).
//
// x:     [128][8192], i = i0*256 + i1*16 + i2   (i0:32, i1:16, i2:16)
// core0: c0[o0*128 + k], k = i0*4 + r1          (o0:32, r1:4)
// core1: c1[(r1*16+o1)*64 + j], j = i1*4 + r2   (o1:16, r2:4)
// core2: c2[r2*256 + o2*16 + i2]                (o2:16)
// out:   [128][8192], o = o0*256 + o1*16 + o2
//
// Block (t, o2-quarter q), 512 thr (8 waves):
//   B: y1[j(64)][col(128)] scalar, written as bf16 hi/lo planes in MFMA
//      B-fragment order (16 B/lane chunks, conflict-free).
//   C: y2 = c1 . y1 via mfma_f32_16x16x32_bf16 (bf16x3); A-frags in VGPRs.
//      reg quad = k-quad contiguous -> one float4 store per tile into y2t.
//   D: out = c0 . y2 + bias, scalar FMA; y2t[dcol][k pad 140] b128 reads.

typedef float  f32x4 __attribute__((ext_vector_type(4)));
typedef __bf16 bf16x8 __attribute__((ext_vector_type(8)));

__device__ __forceinline__ float dot4(float4 a, float4 b) {
    return a.x*b.x + a.y*b.y + a.z*b.z + a.w*b.w;
}

__global__ __launch_bounds__(512, 2) void tt_fused(
    const float* __restrict__ x, const float* __restrict__ c0,
    const float* __restrict__ c1, const float* __restrict__ c2,
    const float* __restrict__ bias, float* __restrict__ out)
{
    __shared__ bf16x8 y1f[2048];                 // [cg(16)][plane(2)][lane(64)], 32 KB
    __shared__ __align__(16) float y2t[8960];    // [dcol(64)][k(128) pad->140], 35 KB

    const int tid = threadIdx.x;
    const int w = tid >> 6, lane = tid & 63;
    const int g = lane >> 4, n = lane & 15;
    const int b = blockIdx.x;
    const int t = b >> 2, q = b & 3;

    // ---- A-fragments (c1, hi/lo) for phase C — early, VMEM overlaps B ------
    const int tile_m = w >> 1;
    bf16x8 Ah[2], Al[2];
    {
        const int m = tile_m*16 + n;             // m-order: m = o1*4 + r1
        const int r1 = m & 3, o1 = m >> 2;
        const float* cp = c1 + (r1*16 + o1)*64 + 8*g;
#pragma unroll
        for (int s = 0; s < 2; ++s) {
            float4 a0 = *reinterpret_cast<const float4*>(cp + 32*s);
            float4 a1 = *reinterpret_cast<const float4*>(cp + 32*s + 4);
            const float av[8] = {a0.x,a0.y,a0.z,a0.w, a1.x,a1.y,a1.z,a1.w};
#pragma unroll
            for (int d = 0; d < 8; ++d) {
                __bf16 h = (__bf16)av[d];
                Ah[s][d] = h;
                Al[s][d] = (__bf16)(av[d] - (float)h);
            }
        }
    }

    // ---- Phase B: y1 fragments, 2 chunks/thread; x slices sequential -------
    {
        const int o2 = q*4 + (n & 3);
#pragma unroll
        for (int c = 0; c < 2; ++c) {
            const int cg = 2*w + c;
            const int s = cg >> 3, tn = cg & 7;
            const int i0 = tn*4 + (n >> 2);
            const int i1b = 8*s + 2*g;           // two consecutive i1 slices
            const float* xp = x + t*8192 + i0*256 + i1b*16;
            float sv[8];
            {   // slice i1b: 4 x-quads live
                const float4 x0 = *reinterpret_cast<const float4*>(xp + 0);
                const float4 x1 = *reinterpret_cast<const float4*>(xp + 4);
                const float4 x2 = *reinterpret_cast<const float4*>(xp + 8);
                const float4 x3 = *reinterpret_cast<const float4*>(xp + 12);
#pragma unroll
                for (int r2 = 0; r2 < 4; ++r2) { // c2: 4-addr broadcast, L1
                    const float4* cb =
                        reinterpret_cast<const float4*>(c2 + r2*256 + o2*16);
                    sv[r2] = dot4(x0,cb[0]) + dot4(x1,cb[1])
                           + dot4(x2,cb[2]) + dot4(x3,cb[3]);
                }
            }
            {   // slice i1b+1
                const float4 x0 = *reinterpret_cast<const float4*>(xp + 16);
                const float4 x1 = *reinterpret_cast<const float4*>(xp + 20);
                const float4 x2 = *reinterpret_cast<const float4*>(xp + 24);
                const float4 x3 = *reinterpret_cast<const float4*>(xp + 28);
#pragma unroll
                for (int r2 = 0; r2 < 4; ++r2) {
                    const float4* cb =
                        reinterpret_cast<const float4*>(c2 + r2*256 + o2*16);
                    sv[4+r2] = dot4(x0,cb[0]) + dot4(x1,cb[1])
                             + dot4(x2,cb[2]) + dot4(x3,cb[3]);
                }
            }
            bf16x8 hi, lo;
#pragma unroll
            for (int d = 0; d < 8; ++d) {
                __bf16 h = (__bf16)sv[d];
                hi[d] = h;
                lo[d] = (__bf16)(sv[d] - (float)h);
            }
            y1f[(cg*2 + 0)*64 + lane] = hi;      // stride-16B: conflict-free
            y1f[(cg*2 + 1)*64 + lane] = lo;
        }
    }
    __syncthreads();

    // ---- Phase C: MFMA, 24 per wave (4 n-tiles x 2 K-steps x 3 split) ------
    {
        const int tnb = (w & 1)*4;
        f32x4 acc[4] = {{0,0,0,0},{0,0,0,0},{0,0,0,0},{0,0,0,0}};
#pragma unroll
        for (int tt = 0; tt < 4; ++tt) {
#pragma unroll
            for (int s = 0; s < 2; ++s) {
                const int cg = s*8 + tnb + tt;
                const bf16x8 Bh = y1f[(cg*2 + 0)*64 + lane];
                const bf16x8 Bl = y1f[(cg*2 + 1)*64 + lane];
                acc[tt] = __builtin_amdgcn_mfma_f32_16x16x32_bf16(Ah[s], Bh, acc[tt], 0, 0, 0);
                acc[tt] = __builtin_amdgcn_mfma_f32_16x16x32_bf16(Ah[s], Bl, acc[tt], 0, 0, 0);
                acc[tt] = __builtin_amdgcn_mfma_f32_16x16x32_bf16(Al[s], Bh, acc[tt], 0, 0, 0);
            }
        }
        // reg r <-> row m = tile_m*16 + g*4 + r -> r1 = r, o1 = tile_m*4 + g:
        // 4 regs = k-quad contiguous -> one float4 per tile.
        const int dcol = (tile_m*4 + g)*4 + (n & 3);
#pragma unroll
        for (int tt = 0; tt < 4; ++tt) {
            const int i0 = (tnb + tt)*4 + (n >> 2);
            *reinterpret_cast<float4*>(y2t + dcol*140 + i0*4) =
                make_float4(acc[tt][0], acc[tt][1], acc[tt][2], acc[tt][3]);
        }
    }
    __syncthreads();

    // ---- Phase D: out = c0 . y2 + bias (scalar FMA) ------------------------
    {
        const int o0q = w;                        // wave-grouped rows
        const int dcol = lane;
        const float* yrow = y2t + dcol*140;
        const float* c0p = c0 + o0q*4*128;
        float a0 = 0.f, a1 = 0.f, a2 = 0.f, a3 = 0.f;
#pragma unroll 4
        for (int kq = 0; kq < 32; ++kq) {
            const float4 yv = *reinterpret_cast<const float4*>(yrow + kq*4);
            const float4 q0 = *reinterpret_cast<const float4*>(c0p + 0*128 + kq*4);
            const float4 q1 = *reinterpret_cast<const float4*>(c0p + 1*128 + kq*4);
            const float4 q2 = *reinterpret_cast<const float4*>(c0p + 2*128 + kq*4);
            const float4 q3 = *reinterpret_cast<const float4*>(c0p + 3*128 + kq*4);
            a0 += dot4(q0, yv); a1 += dot4(q1, yv);
            a2 += dot4(q2, yv); a3 += dot4(q3, yv);
        }
        const int ob = o0q*1024 + (dcol >> 2)*16 + q*4 + (dcol & 3);
        float* op = out + t*8192 + ob;
        op[0]   = a0 + bias[ob];
        op[256] = a1 + bias[ob + 256];
        op[512] = a2 + bias[ob + 512];
        op[768] = a3 + bias[ob + 768];
    }
}

extern "C" void kernel_launch(void* const* d_in, const int* in_sizes, int n_in,
                              void* d_out, int out_size, void* d_ws, size_t ws_size,
                              hipStream_t stream) {
    const float* x    = (const float*)d_in[0];
    const float* c0   = (const float*)d_in[1];
    const float* c1   = (const float*)d_in[2];
    const float* c2   = (const float*)d_in[3];
    const float* bias = (const float*)d_in[4];
    float* out = (float*)d_out;
    (void)d_ws; (void)ws_size;    // no workspace — intermediates live in LDS

    tt_fused<<<512, 512, 0, stream>>>(x, c0, c1, c2, bias, out);
}